// Round 1
// baseline (1683.612 us; speedup 1.0000x reference)
//
#include <hip/hip_runtime.h>
#include <math.h>

#define C   256
#define C8  32
#define B   4
#define N   4096   // H*W
#define TI  32
#define TJ  256

// ---------------------------------------------------------------------------
// Kernel 1: fused 1x1-conv projections f,g,v.
// grid (N/64, B), block 256 (4 waves).
// x: [B][C][N]; wf,wg: [C8][C]; wh: [C][C]
// out: f,g: [B][C8][N]; vt: [B][N][C] (v transposed for coalesced attn reads)
// Each wave owns 80 wave-uniform rows (w accesses -> s_load), 16-row register
// blocking amortizes the LDS x reads (1 ds_read per 16 FMA).
// ---------------------------------------------------------------------------
__global__ __launch_bounds__(256, 2)
void fgv_kernel(const float* __restrict__ x,
                const float* __restrict__ wf, const float* __restrict__ bf,
                const float* __restrict__ wg, const float* __restrict__ bg,
                const float* __restrict__ wh, const float* __restrict__ bh,
                float* __restrict__ f, float* __restrict__ g,
                float* __restrict__ vt)
{
    __shared__ float xs[C * 65];          // [c][n] pad 65 -> conflict-free
    const int n0  = blockIdx.x * 64;
    const int b   = blockIdx.y;
    const int tid = threadIdx.x;

    // ---- stage x tile [256 c][64 n], coalesced ----
    {
        const int n  = tid & 63;
        const int c0 = (tid >> 6) * 64;
        const float* xp = x + (size_t)b * C * N + n0 + n;
        for (int cc = 0; cc < 64; ++cc)
            xs[(c0 + cc) * 65 + n] = xp[(size_t)(c0 + cc) * N];
    }
    __syncthreads();

    const int wv   = __builtin_amdgcn_readfirstlane(threadIdx.x >> 6); // wave 0..3
    const int lane = tid & 63;

    float accv[64];   // v-rows for this thread (mb = 1..4)

    for (int mb = 0; mb < 5; ++mb) {
        // wave-uniform row pointers + biases for this 16-row block
        const float* wp[16];
        float bias[16];
#pragma unroll
        for (int j = 0; j < 16; ++j) {
            int r = wv + 4 * (mb * 16 + j);
            if (r < 32)      { wp[j] = wf + r * C;        bias[j] = bf[r]; }
            else if (r < 64) { wp[j] = wg + (r - 32) * C; bias[j] = bg[r - 32]; }
            else             { wp[j] = wh + (r - 64) * C; bias[j] = bh[r - 64]; }
        }
        float acc[16];
#pragma unroll
        for (int j = 0; j < 16; ++j) acc[j] = 0.f;

        for (int c = 0; c < C; ++c) {
            float xv = xs[c * 65 + lane];
#pragma unroll
            for (int j = 0; j < 16; ++j)
                acc[j] += wp[j][c] * xv;   // wp[j][c] wave-uniform -> s_load
        }

        if (mb == 0) {
            // rows 0..63: f (r<32) and g (32<=r<64), coalesced stores
#pragma unroll
            for (int j = 0; j < 16; ++j) {
                int r = wv + 4 * j;
                float val = acc[j] + bias[j];
                if (r < 32)
                    f[(size_t)(b * C8 + r) * N + n0 + lane] = val;
                else
                    g[(size_t)(b * C8 + (r - 32)) * N + n0 + lane] = val;
            }
        } else {
#pragma unroll
            for (int j = 0; j < 16; ++j)
                accv[(mb - 1) * 16 + j] = acc[j] + bias[j];
        }
    }

    // ---- transpose v through LDS (reuse xs), write vt[b][n][c] coalesced ----
    __syncthreads();
#pragma unroll
    for (int m = 0; m < 64; ++m) {
        int c_out = wv + 64 * (m >> 4) + 4 * (m & 15);
        xs[c_out * 65 + lane] = accv[m];
    }
    __syncthreads();
    {
        float* vp = vt + (size_t)b * N * C + (size_t)n0 * C + tid;
        for (int n = 0; n < 64; ++n)
            vp[(size_t)n * C] = xs[tid * 65 + n];
    }
}

// ---------------------------------------------------------------------------
// Kernel 2: streaming (flash-style) attention, no online max needed
// (|score| <~ 35 -> exp fits fp32 with huge margin).
// grid (N/TI, B), block 256. Thread role:
//   phase A: thread t computes 32 scores for key column j0+t -> Ps[j][i]
//   phase B: thread c accumulates O[i] += e^s * vt[j][c]  (coalesced v reads)
// out[b][c][i] = gamma * O[i]/den[i] + x[b][c][i]
// ---------------------------------------------------------------------------
__global__ __launch_bounds__(256, 2)
void attn_kernel(const float* __restrict__ f, const float* __restrict__ g,
                 const float* __restrict__ vt, const float* __restrict__ x,
                 const float* __restrict__ gamma_p, float* __restrict__ out)
{
    __shared__ float Fs[TI * C8];        // [i][k], rows 128B (16B aligned)
    __shared__ float Ps[TJ * 36];        // [j][i], pad 36 -> aligned b128 rows
    __shared__ float red[8 * TI];
    __shared__ float inv_den[TI];

    const int b   = blockIdx.y;
    const int i0  = blockIdx.x * TI;
    const int tid = threadIdx.x;

    // ---- load F tile: Fs[i][k] = f[b][k][i0+i] ----
    {
        int i = tid & 31, k0 = (tid >> 5) * 4;
        const float* fp = f + (size_t)b * C8 * N + i0 + i;
#pragma unroll
        for (int kk = 0; kk < 4; ++kk)
            Fs[i * C8 + k0 + kk] = fp[(size_t)(k0 + kk) * N];
    }

    float O[TI], dden[TI];
#pragma unroll
    for (int i = 0; i < TI; ++i) { O[i] = 0.f; dden[i] = 0.f; }

    __syncthreads();

    const float* gb = g + (size_t)b * C8 * N;
    const float* vb = vt + (size_t)b * N * C;

    for (int j0 = 0; j0 < N; j0 += TJ) {
        // -------- phase A: scores for key column j = j0 + tid --------
        float gk[C8];
#pragma unroll
        for (int k = 0; k < C8; ++k)
            gk[k] = gb[(size_t)k * N + j0 + tid];       // coalesced

#pragma unroll
        for (int i = 0; i < TI; ++i) {
            const float4* fr = (const float4*)&Fs[i * C8];
            float s = 0.f;
#pragma unroll
            for (int u = 0; u < 8; ++u) {
                float4 fv = fr[u];                       // LDS broadcast
                s += fv.x * gk[4*u] + fv.y * gk[4*u+1]
                   + fv.z * gk[4*u+2] + fv.w * gk[4*u+3];
            }
            float p = __expf(s);
            Ps[tid * 36 + i] = p;
            dden[i] += p;
        }
        __syncthreads();

        // -------- phase B: O[i] += p[j][i] * v[c=tid][j] --------
        for (int j = 0; j < TJ; ++j) {
            float vv = vb[(size_t)(j0 + j) * C + tid];   // coalesced
            const float4* pr = (const float4*)&Ps[j * 36];
#pragma unroll
            for (int u = 0; u < 8; ++u) {
                float4 pv = pr[u];                       // LDS broadcast b128
                O[4*u]   += pv.x * vv;
                O[4*u+1] += pv.y * vv;
                O[4*u+2] += pv.z * vv;
                O[4*u+3] += pv.w * vv;
            }
        }
        __syncthreads();
    }

    // ---- denominator reduction: den[i] = sum over all 256 j-threads ----
#pragma unroll
    for (int i = 0; i < TI; ++i) Ps[tid * 36 + i] = dden[i];
    __syncthreads();
    {
        int i = tid & 31, sl = tid >> 5;
        float s = 0.f;
        for (int u = 0; u < 32; ++u) s += Ps[(sl * 32 + u) * 36 + i];
        red[sl * TI + i] = s;
    }
    __syncthreads();
    if (tid < TI) {
        float t2 = 0.f;
#pragma unroll
        for (int sl = 0; sl < 8; ++sl) t2 += red[sl * TI + tid];
        inv_den[tid] = gamma_p[0] / t2;   // fold gamma into the normalizer
    }
    __syncthreads();

    // ---- scale, transpose through LDS (reuse Ps as Os[256][33]) ----
#pragma unroll
    for (int i = 0; i < TI; ++i)
        Ps[tid * 33 + i] = O[i] * inv_den[i];
    __syncthreads();
    {
        int il = tid & 31, cg = tid >> 5;
        const float* xb = x + (size_t)b * C * N;
        float* ob = out + (size_t)b * C * N;
        for (int cc = cg * 32; cc < cg * 32 + 32; ++cc) {
            float val = Ps[cc * 33 + il];
            ob[(size_t)cc * N + i0 + il] = val + xb[(size_t)cc * N + i0 + il];
        }
    }
}

extern "C" void kernel_launch(void* const* d_in, const int* in_sizes, int n_in,
                              void* d_out, int out_size, void* d_ws, size_t ws_size,
                              hipStream_t stream)
{
    const float* x     = (const float*)d_in[0];
    const float* wf    = (const float*)d_in[1];
    const float* bf    = (const float*)d_in[2];
    const float* wg    = (const float*)d_in[3];
    const float* bg    = (const float*)d_in[4];
    const float* wh    = (const float*)d_in[5];
    const float* bh    = (const float*)d_in[6];
    const float* gamma = (const float*)d_in[7];
    float* out = (float*)d_out;

    float* f  = (float*)d_ws;                       // B*C8*N
    float* g  = f + (size_t)B * C8 * N;             // B*C8*N
    float* vt = g + (size_t)B * C8 * N;             // B*N*C

    fgv_kernel<<<dim3(N / 64, B), 256, 0, stream>>>(x, wf, bf, wg, bg, wh, bh,
                                                    f, g, vt);
    attn_kernel<<<dim3(N / TI, B), 256, 0, stream>>>(f, g, vt, x, gamma, out);
}

// Round 2
// 311.219 us; speedup vs baseline: 5.4097x; 5.4097x over previous
//
#include <hip/hip_runtime.h>
#include <hip/hip_bf16.h>
#include <math.h>

#define C    256
#define C8   32
#define B    4
#define N    4096
#define TI   32      // queries per attn block
#define TJ   64      // keys per j-iteration

typedef __attribute__((ext_vector_type(8))) short bf16x8;
typedef __attribute__((ext_vector_type(4))) short bf16x4;
typedef __attribute__((ext_vector_type(4))) float f32x4;

__device__ inline unsigned short f2bf(float x) {
    union { float f; unsigned u; } v; v.f = x;
    unsigned r = v.u + 0x7fffu + ((v.u >> 16) & 1u);   // RNE (inputs finite)
    return (unsigned short)(r >> 16);
}

// ---------------------------------------------------------------------------
// Kernel 1: projections f,g,v (fp32 VALU, only 2.7 GF) -> MFMA-ready bf16:
//   ft,gt: [B][N][32]  (row = 64 B; A/B fragments are one b128 read)
//   vb:    [B][C][N]   (PV B-fragments read 16 contiguous B per lane)
// grid (64 n-tiles, 10 row-groups, B) = 2560 blocks -> 2 blocks/CU (LDS cap).
// rg0 = f rows, rg1 = g rows, rg2..9 = v rows 32 each.
// ---------------------------------------------------------------------------
__global__ __launch_bounds__(256, 2)
void fgv_kernel(const float* __restrict__ x,
                const float* __restrict__ wf, const float* __restrict__ bf_,
                const float* __restrict__ wg, const float* __restrict__ bg,
                const float* __restrict__ wh, const float* __restrict__ bh,
                unsigned short* __restrict__ ft, unsigned short* __restrict__ gt,
                unsigned short* __restrict__ vb)
{
    __shared__ float xs[256 * 68];           // [c][n] pad 68 (16B-aligned rows)
    __shared__ unsigned short ts[64 * 40];   // transpose buf [n][k] pad 40

    const int nt  = blockIdx.x;              // n-tile
    const int rg  = blockIdx.y;              // row group 0..9
    const int b   = blockIdx.z;
    const int n0  = nt * 64;
    const int tid = threadIdx.x;

    // ---- stage x tile [256 c][64 n], float4-coalesced ----
    {
        const float* xp = x + ((size_t)b * C + (tid >> 4)) * N + n0 + (tid & 15) * 4;
        float*       dp = &xs[(tid >> 4) * 68 + (tid & 15) * 4];
#pragma unroll
        for (int r = 0; r < 16; ++r)
            *(float4*)(dp + r * 16 * 68) = *(const float4*)(xp + (size_t)r * 16 * N);
    }
    __syncthreads();

    const int wv   = __builtin_amdgcn_readfirstlane(tid >> 6);
    const int lane = tid & 63;
    const int r0   = wv * 8;                 // 8 rows per wave

    const float* wbase; const float* bbase;
    if (rg == 0)      { wbase = wf; bbase = bf_; }
    else if (rg == 1) { wbase = wg; bbase = bg; }
    else              { wbase = wh + (size_t)(rg - 2) * 32 * C; bbase = bh + (rg - 2) * 32; }

    float acc[8];
#pragma unroll
    for (int j = 0; j < 8; ++j) acc[j] = bbase[r0 + j];

    const float* w0 = wbase + (size_t)r0 * C;  // wave-uniform -> s_loads
#pragma unroll 4
    for (int c = 0; c < C; ++c) {
        float xv = xs[c * 68 + lane];
#pragma unroll
        for (int j = 0; j < 8; ++j)
            acc[j] += w0[j * C + c] * xv;
    }

    if (rg <= 1) {
        // transpose [k][n] -> [n][k] via LDS, write bf16 rows of 64 B
        bf16x8 pk;
#pragma unroll
        for (int j = 0; j < 8; ++j) pk[j] = (short)f2bf(acc[j]);
        *(bf16x8*)&ts[lane * 40 + r0] = pk;       // ds_write_b128
        __syncthreads();
        unsigned short* dst = (rg == 0 ? ft : gt) + ((size_t)b * N + n0) * 32;
        *(int4*)(dst + (size_t)(tid >> 2) * 32 + (tid & 3) * 8) =
            *(const int4*)(&ts[(tid >> 2) * 40 + (tid & 3) * 8]);
    } else {
        const int c0 = (rg - 2) * 32 + r0;
        unsigned short* vp = vb + ((size_t)b * C + c0) * N + n0 + lane;
#pragma unroll
        for (int j = 0; j < 8; ++j)
            vp[(size_t)j * N] = f2bf(acc[j]);
    }
}

// ---------------------------------------------------------------------------
// Kernel 2: flash-style MFMA attention. Block = (batch, 32-query tile),
// 256 threads = 4 waves. Per j-iter (TJ=64):
//   wave w: S^T(16x32) = G_A(j-subtile w) x F_B (2 MFMA, K=32 one-shot)
//           exp -> pack bf16 -> ds_write_b64 into double-buffered Ps
//   barrier; PV: P A-frags from Ps, V B-frags DIRECT from global (L2),
//           16 MFMA/wave into 8 fp32x4 accums (wave owns 64 c-channels).
// No online max: |scores| <~ 35 -> exp fits fp32/bf16 with huge margin.
// Epilogue: shuffle+LDS den reduce, gamma/den fold, Os transpose, coalesced
// float4 out = scaled O + x.
// Batch->XCD swizzle: b = blk&3 keeps each batch's v(2MB)+g(256KB) in one
// XCD's 4MB L2.
// ---------------------------------------------------------------------------
__global__ __launch_bounds__(256, 2)
void attn_kernel(const unsigned short* __restrict__ ft,
                 const unsigned short* __restrict__ gt,
                 const unsigned short* __restrict__ vb,
                 const float* __restrict__ x,
                 const float* __restrict__ gamma_p,
                 float* __restrict__ out)
{
    __shared__ unsigned short Ps[2][TI * 72];   // [i][j] bf16, 144B rows
    __shared__ float red[4][TI];
    __shared__ float invd[TI];
    __shared__ float Os[C * 36];                // [c][i] fp32, 144B rows

    const int blk  = blockIdx.x;
    const int b    = blk & 3;                   // XCD-swizzled batch
    const int i0   = (blk >> 2) * TI;
    const int tid  = threadIdx.x;
    const int wv   = tid >> 6;
    const int lane = tid & 63;
    const int q    = lane >> 4;                 // quad
    const int r    = lane & 15;

    // ---- preload F B-fragments (reused across all j-tiles) ----
    bf16x8 fB[2];
#pragma unroll
    for (int it = 0; it < 2; ++it)
        fB[it] = *(const bf16x8*)(ft + ((size_t)b * N + i0 + it * 16 + r) * 32 + q * 8);

    f32x4 Oacc[2][4];
#pragma unroll
    for (int it = 0; it < 2; ++it)
#pragma unroll
        for (int ct = 0; ct < 4; ++ct)
            Oacc[it][ct] = (f32x4){0.f, 0.f, 0.f, 0.f};
    float dden[2] = {0.f, 0.f};

    const unsigned short* gbase = gt + (size_t)b * N * 32;
    const unsigned short* vbase = vb + (size_t)b * C * N;
    const int c0 = wv * 64;                     // this wave's channel range

    for (int jt = 0; jt < N / TJ; ++jt) {
        const int j0 = jt * TJ;
        unsigned short* PsBuf = Ps[jt & 1];

        // ---- scores (transposed): S^T[j][i] = sum_k g[k][j] f[k][i] ----
        bf16x8 gA = *(const bf16x8*)(gbase + (size_t)(j0 + wv * 16 + r) * 32 + q * 8);
#pragma unroll
        for (int it = 0; it < 2; ++it) {
            f32x4 s = (f32x4){0.f, 0.f, 0.f, 0.f};
            s = __builtin_amdgcn_mfma_f32_16x16x32_bf16(gA, fB[it], s, 0, 0, 0);
            bf16x4 pk;
#pragma unroll
            for (int u = 0; u < 4; ++u) {
                float p = __expf(s[u]);
                dden[it] += p;                  // partial den for i = it*16 + r
                pk[u] = (short)f2bf(p);
            }
            // C-frag rows are consecutive j -> one b64 write
            *(bf16x4*)&PsBuf[(it * 16 + r) * 72 + wv * 16 + q * 4] = pk;
        }
        __syncthreads();                        // single barrier (Ps dbuf)

        // ---- PV: O[i][c] += P[i][j] * v[c][j] ----
#pragma unroll
        for (int kc = 0; kc < 2; ++kc) {
            bf16x8 pA[2];
#pragma unroll
            for (int it = 0; it < 2; ++it)
                pA[it] = *(const bf16x8*)&PsBuf[(it * 16 + r) * 72 + kc * 32 + q * 8];
#pragma unroll
            for (int ct = 0; ct < 4; ++ct) {
                bf16x8 vB = *(const bf16x8*)(vbase +
                    (size_t)(c0 + ct * 16 + r) * N + j0 + kc * 32 + q * 8);
#pragma unroll
                for (int it = 0; it < 2; ++it)
                    Oacc[it][ct] = __builtin_amdgcn_mfma_f32_16x16x32_bf16(
                        pA[it], vB, Oacc[it][ct], 0, 0, 0);
            }
        }
    }

    // ---- denominator: reduce quads (shuffle) then waves (LDS) ----
#pragma unroll
    for (int it = 0; it < 2; ++it) {
        float v = dden[it];
        v += __shfl_xor(v, 16, 64);
        v += __shfl_xor(v, 32, 64);
        if (q == 0) red[wv][it * 16 + r] = v;
    }
    __syncthreads();
    if (tid < TI) {
        float s = red[0][tid] + red[1][tid] + red[2][tid] + red[3][tid];
        invd[tid] = gamma_p[0] / s;             // fold gamma; den>0 always
    }
    __syncthreads();

    // ---- scale accums, transpose through Os[c][i] ----
#pragma unroll
    for (int it = 0; it < 2; ++it) {
        float iv[4];
#pragma unroll
        for (int u = 0; u < 4; ++u) iv[u] = invd[it * 16 + q * 4 + u]; // LDS bcast
#pragma unroll
        for (int ct = 0; ct < 4; ++ct) {
            f32x4 o = Oacc[it][ct];
            f32x4 w;
#pragma unroll
            for (int u = 0; u < 4; ++u) w[u] = o[u] * iv[u];
            *(f32x4*)&Os[(size_t)(c0 + ct * 16 + r) * 36 + it * 16 + q * 4] = w;
        }
    }
    __syncthreads();

    // ---- out = Os + x, fully-coalesced float4 rows ----
    const float* xb = x  + (size_t)b * C * N + i0;
    float*       ob = out + (size_t)b * C * N + i0;
#pragma unroll
    for (int rd = 0; rd < 8; ++rd) {
        const int c  = (tid >> 3) + rd * 32;
        const int ic = (tid & 7) * 4;
        f32x4 ov = *(const f32x4*)&Os[(size_t)c * 36 + ic];
        f32x4 xv = *(const f32x4*)(xb + (size_t)c * N + ic);
        f32x4 rs;
#pragma unroll
        for (int u = 0; u < 4; ++u) rs[u] = ov[u] + xv[u];
        *(f32x4*)(ob + (size_t)c * N + ic) = rs;
    }
}

extern "C" void kernel_launch(void* const* d_in, const int* in_sizes, int n_in,
                              void* d_out, int out_size, void* d_ws, size_t ws_size,
                              hipStream_t stream)
{
    (void)in_sizes; (void)n_in; (void)out_size; (void)ws_size;
    const float* x     = (const float*)d_in[0];
    const float* wf    = (const float*)d_in[1];
    const float* bf_   = (const float*)d_in[2];
    const float* wg    = (const float*)d_in[3];
    const float* bg    = (const float*)d_in[4];
    const float* wh    = (const float*)d_in[5];
    const float* bh    = (const float*)d_in[6];
    const float* gamma = (const float*)d_in[7];
    float* out = (float*)d_out;

    unsigned short* ft = (unsigned short*)d_ws;            // B*N*32 bf16 = 1 MB
    unsigned short* gt = ft + (size_t)B * N * 32;          // 1 MB
    unsigned short* vb = gt + (size_t)B * N * 32;          // B*C*N bf16 = 8 MB

    fgv_kernel<<<dim3(N / 64, 10, B), 256, 0, stream>>>(x, wf, bf_, wg, bg,
                                                        wh, bh, ft, gt, vb);
    attn_kernel<<<dim3((N / TI) * B), 256, 0, stream>>>(ft, gt, vb, x, gamma, out);
}